// Round 17
// baseline (232.728 us; speedup 1.0000x reference)
//
#include <hip/hip_runtime.h>

#define SEQ 512
#define HD 512
#define BATCH 32
#define TOK (BATCH * SEQ)   // 16384
#define NHEAD 8
#define DKDIM 64
#define MREL 16
#define NRELV 33

using short8 = __attribute__((ext_vector_type(8))) short;
using f32x4  = __attribute__((ext_vector_type(4))) float;
using f32x16 = __attribute__((ext_vector_type(16))) float;
typedef unsigned short ushortT;

#define AS1 __attribute__((address_space(1)))
#define AS3 __attribute__((address_space(3)))
#define GLDS16(g, l) __builtin_amdgcn_global_load_lds( \
    (const AS1 unsigned int*)(const void*)(g), \
    (AS3 unsigned int*)(void*)(l), 16, 0, 0)

__device__ __forceinline__ ushortT f2bf(float x) {
  union { float f; unsigned u; } c; c.f = x;
  unsigned r = c.u + 0x7FFF + ((c.u >> 16) & 1);
  return (ushortT)(r >> 16);
}

__device__ __forceinline__ float bf2f(ushortT h) {
  union { unsigned u; float f; } c; c.u = (unsigned)h << 16;
  return c.f;
}

// ------- merged init: positional-encoding table + weights f32->bf16 ----------
__global__ __launch_bounds__(256) void init_kernel(
    float* __restrict__ PE,
    const float* __restrict__ s0, const float* __restrict__ s1,
    const float* __restrict__ s2, const float* __restrict__ s3,
    const float* __restrict__ s4, const float* __restrict__ s5,
    const float* __restrict__ s6, ushortT* __restrict__ dst) {
  const int b = blockIdx.x;
  const int t = threadIdx.x;
  if (b < SEQ * HD / 256) {                       // PE part
    const int i = b * 256 + t;
    const int s = i >> 9, h = i & (HD - 1);
    float v = 0.f;
    if (s > 0) {
      const int i2 = h & ~1;
      const float div = expf((float)i2 * (-9.210340371976184f / (float)HD));
      const float ang = (float)(s - 1) * div;
      v = (h & 1) ? cosf(ang) : sinf(ang);
    }
    PE[i] = v;
  } else {                                        // weight-convert part
    const int i = (b - SEQ * HD / 256) * 256 + t; // < 7 * HD*HD/4
    const int region = i >> 16;
    const int off = i & 65535;
    const float* s = region == 0 ? s0 : region == 1 ? s1 : region == 2 ? s2 :
                     region == 3 ? s3 : region == 4 ? s4 : region == 5 ? s5 : s6;
    const float4 v = ((const float4*)s)[off];
    ushort4 o;
    o.x = f2bf(v.x); o.y = f2bf(v.y); o.z = f2bf(v.z); o.w = f2bf(v.w);
    *(ushort4*)&dst[(long)i * 4] = o;
  }
}

// ---------------- LayerNorm, one block per row; bf16 out ----------------
template <bool BF>
__global__ __launch_bounds__(256) void ln_kernel(
    const float* __restrict__ X, const float* __restrict__ g,
    const float* __restrict__ bta, void* __restrict__ Yv) {
  const int row = blockIdx.x;
  const int t = threadIdx.x;
  const float* xr = X + (long)row * HD;
  const float x0 = xr[t], x1 = xr[t + 256];
  float s = x0 + x1, q = x0 * x0 + x1 * x1;
  #pragma unroll
  for (int off = 32; off > 0; off >>= 1) {
    s += __shfl_down(s, off);
    q += __shfl_down(q, off);
  }
  __shared__ float sh[10];
  const int w = t >> 6;
  if ((t & 63) == 0) { sh[w] = s; sh[4 + w] = q; }
  __syncthreads();
  if (t == 0) {
    const float S_ = sh[0] + sh[1] + sh[2] + sh[3];
    const float Q_ = sh[4] + sh[5] + sh[6] + sh[7];
    const float mu = S_ * (1.f / (float)HD);
    const float var = Q_ * (1.f / (float)HD) - mu * mu;
    sh[8] = mu;
    sh[9] = rsqrtf(var + 1e-5f);
  }
  __syncthreads();
  const float mu = sh[8], rstd = sh[9];
  const float y0 = (x0 - mu) * rstd * g[t] + bta[t];
  const float y1 = (x1 - mu) * rstd * g[t + 256] + bta[t + 256];
  if (BF) {
    ushortT* yr = (ushortT*)Yv + (long)row * HD;
    yr[t] = f2bf(y0);
    yr[t + 256] = f2bf(y1);
  } else {
    float* yr = (float*)Yv + (long)row * HD;
    yr[t] = y0;
    yr[t + 256] = y1;
  }
}

// ---- fused [addpos +] LayerNorm + depthwise conv1d (K=7, pad 3) ----
template <bool ADDPE>
__global__ __launch_bounds__(256) void lndw_kernel(
    const float* __restrict__ X, const float* __restrict__ PE,
    const int* __restrict__ mask, const float* __restrict__ g,
    const float* __restrict__ bta, const float* __restrict__ w,
    const float* __restrict__ bias, ushortT* __restrict__ Hout) {
  __shared__ ushortT nls[22][512];        // 22528 B
  const int t = threadIdx.x;
  const int lane = t & 63, wv = t >> 6;
  const int tile = blockIdx.x;            // b*32 + stile
  const int b = tile >> 5;
  const int s0 = (tile & 31) << 4;
  const long rowb = (long)b * SEQ;

  float gr[8], br[8];
  #pragma unroll
  for (int i = 0; i < 2; ++i) {
    const float4 v = *(const float4*)&g[lane * 8 + i * 4];
    gr[i * 4 + 0] = v.x; gr[i * 4 + 1] = v.y; gr[i * 4 + 2] = v.z; gr[i * 4 + 3] = v.w;
    const float4 u = *(const float4*)&bta[lane * 8 + i * 4];
    br[i * 4 + 0] = u.x; br[i * 4 + 1] = u.y; br[i * 4 + 2] = u.z; br[i * 4 + 3] = u.w;
  }

  const short8 zero8 = {};
  for (int rr = wv; rr < 22; rr += 4) {
    const int ss = s0 - 3 + rr;
    if (ss < 0 || ss >= SEQ) {
      *(short8*)&nls[rr][lane * 8] = zero8;
    } else {
      const float* xr = X + (rowb + ss) * HD + lane * 8;
      const float4 v0 = *(const float4*)xr;
      const float4 v1 = *(const float4*)(xr + 4);
      float xv[8] = {v0.x, v0.y, v0.z, v0.w, v1.x, v1.y, v1.z, v1.w};
      if (ADDPE) {
        const float mk = (float)mask[rowb + ss];
        const float4 p0 = *(const float4*)&PE[(long)ss * HD + lane * 8];
        const float4 p1 = *(const float4*)&PE[(long)ss * HD + lane * 8 + 4];
        xv[0] += p0.x * mk; xv[1] += p0.y * mk; xv[2] += p0.z * mk; xv[3] += p0.w * mk;
        xv[4] += p1.x * mk; xv[5] += p1.y * mk; xv[6] += p1.z * mk; xv[7] += p1.w * mk;
      }
      float s = 0.f, q = 0.f;
      #pragma unroll
      for (int j = 0; j < 8; ++j) { s += xv[j]; q += xv[j] * xv[j]; }
      #pragma unroll
      for (int off = 32; off > 0; off >>= 1) {
        s += __shfl_xor(s, off);
        q += __shfl_xor(q, off);
      }
      const float mu = s * (1.f / (float)HD);
      const float var = q * (1.f / (float)HD) - mu * mu;
      const float rstd = rsqrtf(var + 1e-5f);
      short8 o;
      #pragma unroll
      for (int j = 0; j < 8; ++j)
        o[j] = (short)f2bf((xv[j] - mu) * rstd * gr[j] + br[j]);
      *(short8*)&nls[rr][lane * 8] = o;
    }
  }
  __syncthreads();

  const int cg = t & 63, sb = t >> 6;
  const int c0 = cg * 8;
  const int sbase = sb * 4;
  float wr[56];
  #pragma unroll
  for (int i = 0; i < 14; ++i) {
    const float4 v = *(const float4*)&w[c0 * 7 + i * 4];
    wr[i * 4 + 0] = v.x; wr[i * 4 + 1] = v.y;
    wr[i * 4 + 2] = v.z; wr[i * 4 + 3] = v.w;
  }
  float bz[8];
  #pragma unroll
  for (int i = 0; i < 2; ++i) {
    const float4 v = *(const float4*)&bias[c0 + i * 4];
    bz[i * 4 + 0] = v.x; bz[i * 4 + 1] = v.y;
    bz[i * 4 + 2] = v.z; bz[i * 4 + 3] = v.w;
  }

  short8 win[7];
  #pragma unroll
  for (int k = 0; k < 7; ++k)
    win[k] = *(const short8*)&nls[sbase + k][c0];
  #pragma unroll
  for (int u = 0; u < 4; ++u) {
    float acc[8];
    #pragma unroll
    for (int j = 0; j < 8; ++j) acc[j] = bz[j];
    #pragma unroll
    for (int k = 0; k < 7; ++k)
      #pragma unroll
      for (int j = 0; j < 8; ++j)
        acc[j] += bf2f((ushortT)win[k][j]) * wr[j * 7 + k];
    short8 o;
    #pragma unroll
    for (int j = 0; j < 8; ++j) o[j] = (short)f2bf(acc[j]);
    *(short8*)&Hout[(rowb + s0 + sbase + u) * HD + c0] = o;
    if (u < 3) {
      #pragma unroll
      for (int k = 0; k < 6; ++k) win[k] = win[k + 1];
      win[6] = *(const short8*)&nls[sbase + u + 7][c0];
    }
  }
}

// ---- 512-thread (8-wave) GEMM tile body: 128x128, BK=64, 2x4 wave grid ------
__device__ __forceinline__ void gemm_tile512(
    const ushortT* __restrict__ A, const ushortT* __restrict__ W,
    int row0, int col0, int t, ushortT* Als, ushortT* Bls, f32x4 acc[4][2]) {
  const int lane = t & 63, w = t >> 6;
  const int wr = w >> 2, wc = w & 3;          // 2 x 4 waves; wave tile 64x32
  const int l15 = lane & 15, lhi = lane >> 4;
  for (int kt = 0; kt < 8; ++kt) {
    __syncthreads();
    #pragma unroll
    for (int i = 0; i < 2; ++i) {
      const int tl = i * 512 + t;
      const int r = tl >> 3, sl = tl & 7;
      const int sc = sl ^ (r & 7);
      GLDS16(A + (long)(row0 + r) * HD + kt * 64 + sc * 8,
             Als + (i * 512 + w * 64) * 8);
      GLDS16(W + (long)(col0 + r) * HD + kt * 64 + sc * 8,
             Bls + (i * 512 + w * 64) * 8);
    }
    __syncthreads();
    #pragma unroll
    for (int kk = 0; kk < 2; ++kk) {
      short8 af[4], bf[2];
      #pragma unroll
      for (int i = 0; i < 4; ++i) {
        const int ra = wr * 64 + i * 16 + l15;
        af[i] = *(const short8*)&Als[ra * 64 + (((kk * 4 + lhi) ^ (ra & 7)) << 3)];
      }
      #pragma unroll
      for (int j = 0; j < 2; ++j) {
        const int rb = wc * 32 + j * 16 + l15;
        bf[j] = *(const short8*)&Bls[rb * 64 + (((kk * 4 + lhi) ^ (rb & 7)) << 3)];
      }
      #pragma unroll
      for (int mi = 0; mi < 4; ++mi)
        #pragma unroll
        for (int ni = 0; ni < 2; ++ni)
          acc[mi][ni] = __builtin_amdgcn_mfma_f32_16x16x32_bf16(af[mi], bf[ni], acc[mi][ni], 0, 0, 0);
    }
  }
}

// MODE 0: C=G  1: C+=G  2: C+=relu(G)  3: Cb=bf16(G)
// MODE 4: C = (X + PE*mask) + relu(G)   (fused addpos residual, conv block 0)
template <int MODE>
__global__ __launch_bounds__(512) void mgemm512_kernel(
    const ushortT* __restrict__ A, const ushortT* __restrict__ W,
    const float* __restrict__ bias, float* __restrict__ C,
    ushortT* __restrict__ Cb, const float* __restrict__ Xp,
    const float* __restrict__ PEp, const int* __restrict__ maskp) {
  __shared__ ushortT Als[128 * 64];
  __shared__ ushortT Bls[128 * 64];
  const int t = threadIdx.x;
  const int bid = blockIdx.x;
  const int m_blk = (bid & 7) * 16 + ((bid >> 3) & 15);  // XCD-chunked
  const int n_blk = bid >> 7;
  const int row0 = m_blk * 128, col0 = n_blk * 128;
  const int lane = t & 63, w = t >> 6;
  const int wr = w >> 2, wc = w & 3;
  const int l15 = lane & 15, lhi = lane >> 4;

  f32x4 acc[4][2] = {};
  gemm_tile512(A, W, row0, col0, t, Als, Bls, acc);

  #pragma unroll
  for (int ni = 0; ni < 2; ++ni) {
    const int c = col0 + wc * 32 + ni * 16 + l15;
    const float bz = bias[c];
    #pragma unroll
    for (int mi = 0; mi < 4; ++mi) {
      #pragma unroll
      for (int reg = 0; reg < 4; ++reg) {
        const int rrow = row0 + wr * 64 + mi * 16 + lhi * 4 + reg;
        const float g = acc[mi][ni][reg] + bz;
        const long idx = (long)rrow * HD + c;
        if (MODE == 0)      C[idx] = g;
        else if (MODE == 1) C[idx] += g;
        else if (MODE == 2) C[idx] += fmaxf(g, 0.f);
        else if (MODE == 3) Cb[idx] = f2bf(g);
        else {
          const int srow = rrow & (SEQ - 1);
          const float mk = (float)maskp[rrow];
          C[idx] = Xp[idx] + PEp[(long)srow * HD + c] * mk + fmaxf(g, 0.f);
        }
      }
    }
  }
}

// fused QKV (512 threads, 8 waves) writing MFMA-fragment layouts:
// Q/K: off = (((bh*16 + s/32)*4 + dd/16)*2 + (dd/8)&1)*256 + (s%32)*8 + dd%8
// V:   off = (((bh*16 + s/32)*4 + (s%32)/8)*2 + dd/32)*256 + (dd%32)*8 + s%8
__global__ __launch_bounds__(512) void qkv_kernel(
    const ushortT* __restrict__ A, const ushortT* __restrict__ Wbase,
    const float* __restrict__ bq, const float* __restrict__ bk,
    const float* __restrict__ bv, ushortT* __restrict__ Q,
    ushortT* __restrict__ K, ushortT* __restrict__ Vt) {
  __shared__ ushortT Als[128 * 64];
  __shared__ ushortT Bls[128 * 64];
  const int t = threadIdx.x;
  const int z = blockIdx.y;
  const ushortT* W = Wbase + (long)z * HD * HD;
  const float* bias = z == 0 ? bq : z == 1 ? bk : bv;
  const int bid = blockIdx.x;
  const int m_blk = (bid & 7) * 16 + ((bid >> 3) & 15);
  const int n_blk = bid >> 7;
  const int row0 = m_blk * 128, col0 = n_blk * 128;
  const int lane = t & 63, w = t >> 6;
  const int wr = w >> 2, wc = w & 3;
  const int l15 = lane & 15, lhi = lane >> 4;

  f32x4 acc[4][2] = {};
  gemm_tile512(A, W, row0, col0, t, Als, Bls, acc);

  #pragma unroll
  for (int ni = 0; ni < 2; ++ni) {
    const int c = col0 + wc * 32 + ni * 16 + l15;
    const float bz = bias[c];
    #pragma unroll
    for (int mi = 0; mi < 4; ++mi) {
      if (z == 2) {                    // V fragment write (4 consecutive s)
        const int tok0 = row0 + wr * 64 + mi * 16 + lhi * 4;
        const int b = tok0 >> 9, s0 = tok0 & (SEQ - 1);
        const int hh2 = c >> 6, dd = c & 63;
        ushort4 pk;
        pk.x = f2bf(acc[mi][ni][0] + bz);
        pk.y = f2bf(acc[mi][ni][1] + bz);
        pk.z = f2bf(acc[mi][ni][2] + bz);
        pk.w = f2bf(acc[mi][ni][3] + bz);
        const long off = ((((long)(b * NHEAD + hh2) * 16 + (s0 >> 5)) * 4 +
                           ((s0 & 31) >> 3)) * 2 + (dd >> 5)) * 256 +
                         (dd & 31) * 8 + (s0 & 7);
        *(ushort4*)&Vt[off] = pk;
      } else {                          // Q/K fragment write
        ushortT* Cb = (z == 0) ? Q : K;
        const int hh2 = c >> 6, dd = c & 63;
        #pragma unroll
        for (int reg = 0; reg < 4; ++reg) {
          const int rrow = row0 + wr * 64 + mi * 16 + lhi * 4 + reg;
          const int b = rrow >> 9, s = rrow & (SEQ - 1);
          const long off = ((((long)(b * NHEAD + hh2) * 16 + (s >> 5)) * 4 +
                             (dd >> 4)) * 2 + ((dd >> 3) & 1)) * 256 +
                           (s & 31) * 8 + (dd & 7);
          Cb[off] = f2bf(acc[mi][ni][reg] + bz);
        }
      }
    }
  }
}

// ---------------- swapped-QK 32x32 MFMA attention, fragment-layout loads -----
// 4 waves / 256 threads per block (grid 1024): 4-5 blocks/CU resident vs 2,
// raising TLP for this latency-bound kernel. Per-wave logic unchanged.
__global__ __launch_bounds__(256, 5) void attn_kernel(
    const ushortT* __restrict__ Qf, const ushortT* __restrict__ Kf,
    const ushortT* __restrict__ Vf, const float* __restrict__ ekg,
    const float* __restrict__ evg, ushortT* __restrict__ Og) {
  __shared__ ushortT qekL[4][32][34];     // 8704 B
  __shared__ ushortT wsAll[4][32][56];    // 14336 B
  __shared__ ushortT EVT[64][56];         // 7168 B  (EV^T bf16, zero-padded)
  __shared__ float LROWw[4][32];          // 512 B
  __shared__ float WHIw[4][32];           // 512 B

  const int t = threadIdx.x;
  const int lane = t & 63, w = t >> 6;    // w in 0..3
  const int l31 = lane & 31, h = lane >> 5;
  const int hh = blockIdx.x, qb = blockIdx.y, bb = blockIdx.z;
  const int q0w = qb * 128 + w * 32;
  const long qkb = ((long)bb * SEQ) * HD + hh * DKDIM;        // for Og only
  const long fbase = (long)(bb * NHEAD + hh) * 16;            // fragment tiles

  // EVT build (cooperative) + zero own wsAll slice
  for (int i = t; i < 64 * 56; i += 256) {
    const int d = i / 56, r = i % 56;
    EVT[d][r] = (r < NRELV) ? f2bf(evg[r * 64 + d]) : (ushortT)0;
  }
  {
    unsigned* wz = (unsigned*)&wsAll[w][0][0];   // 32*56*2/4 = 896 u32
    #pragma unroll
    for (int i = 0; i < 14; ++i) wz[lane + i * 64] = 0u;
  }
  __syncthreads();

  short8 qB[4];
  #pragma unroll
  for (int kk = 0; kk < 4; ++kk)
    qB[kk] = *(const short8*)&Qf[(((fbase + qb * 4 + w) * 4 + kk) * 2 + h) * 256 + l31 * 8];

  {
    f32x16 qacc = {};
    #pragma unroll
    for (int kk = 0; kk < 4; ++kk) {
      short8 ef;
      #pragma unroll
      for (int j = 0; j < 8; ++j)
        ef[j] = (short)f2bf(ekg[l31 * 64 + kk * 16 + h * 8 + j]);
      qacc = __builtin_amdgcn_mfma_f32_32x32x16_bf16(ef, qB[kk], qacc, 0, 0, 0);
    }
    #pragma unroll
    for (int r = 0; r < 16; ++r) {
      const int rr = (r & 3) + 8 * (r >> 2) + 4 * h;
      qekL[w][l31][rr] = f2bf(qacc[r]);
    }
  }
  float qekHiR = 0.f, qekLoR = 0.f;
  #pragma unroll
  for (int kk = 0; kk < 4; ++kk)
    #pragma unroll
    for (int j = 0; j < 8; ++j) {
      const float qv = bf2f((ushortT)qB[kk][j]);
      const int d = kk * 16 + h * 8 + j;
      qekHiR += qv * ekg[32 * 64 + d];
      qekLoR += qv * ekg[d];
    }
  qekHiR += __shfl_xor(qekHiR, 32);
  qekLoR += __shfl_xor(qekLoR, 32);
  if (h == 0) qekL[w][l31][32] = f2bf(qekHiR);

  const int qg = q0w + l31;
  f32x16 oaccL = {}, oaccH = {};
  float rsum = 0.f, wsHi = 0.f;

  for (int kt = 0; kt < 16; ++kt) {
    const int k0 = kt * 32;
    f32x16 sacc = {};
    __builtin_amdgcn_s_setprio(1);
    #pragma unroll
    for (int kk = 0; kk < 4; ++kk) {
      const short8 kf = *(const short8*)&Kf[(((fbase + kt) * 4 + kk) * 2 + h) * 256 + l31 * 8];
      sacc = __builtin_amdgcn_mfma_f32_32x32x16_bf16(kf, qB[kk], sacc, 0, 0, 0);
    }
    __builtin_amdgcn_s_setprio(0);
    const int dmin = k0 - q0w - 31, dmax = k0 + 31 - q0w;
    if (dmin >= MREL) {
      #pragma unroll
      for (int r = 0; r < 16; ++r) {
        const float p = __expf(sacc[r] + qekHiR);
        sacc[r] = p; rsum += p; wsHi += p;
      }
    } else if (dmax <= -MREL) {
      #pragma unroll
      for (int r = 0; r < 16; ++r) {
        const float p = __expf(sacc[r] + qekLoR);
        sacc[r] = p; rsum += p;
      }
    } else {
      #pragma unroll
      for (int r = 0; r < 16; ++r) {
        const int key = k0 + (r & 3) + 8 * (r >> 2) + 4 * h;
        const int db = key - qg;
        const int rcl = min(max(db, -MREL), MREL) + MREL;
        const float p = __expf(sacc[r] + bf2f(qekL[w][l31][rcl]));
        sacc[r] = p; rsum += p;
        if (db >= MREL)       wsHi += p;
        else if (db > -MREL)  wsAll[w][l31][db + MREL] = f2bf(p);  // slots 1..31
      }
    }
    #pragma unroll
    for (int c = 0; c < 2; ++c) {
      const int rb = c * 8;
      unsigned a0, a1, b0, b1;
      asm("v_cvt_pk_bf16_f32 %0, %1, %2" : "=v"(a0) : "v"(sacc[rb + 0]), "v"(sacc[rb + 1]));
      asm("v_cvt_pk_bf16_f32 %0, %1, %2" : "=v"(a1) : "v"(sacc[rb + 2]), "v"(sacc[rb + 3]));
      asm("v_cvt_pk_bf16_f32 %0, %1, %2" : "=v"(b0) : "v"(sacc[rb + 4]), "v"(sacc[rb + 5]));
      asm("v_cvt_pk_bf16_f32 %0, %1, %2" : "=v"(b1) : "v"(sacc[rb + 6]), "v"(sacc[rb + 7]));
      asm("v_permlane32_swap_b32 %0, %1" : "+v"(a0), "+v"(b0));
      asm("v_permlane32_swap_b32 %0, %1" : "+v"(a1), "+v"(b1));
      union { unsigned u[4]; short8 s; } pa;
      pa.u[0] = a0; pa.u[1] = a1; pa.u[2] = b0; pa.u[3] = b1;
      const short8 v0 = *(const short8*)&Vf[((((fbase + kt) * 4 + c * 2 + h) * 2 + 0) * 256) + l31 * 8];
      const short8 v1 = *(const short8*)&Vf[((((fbase + kt) * 4 + c * 2 + h) * 2 + 1) * 256) + l31 * 8];
      __builtin_amdgcn_s_setprio(1);
      oaccL = __builtin_amdgcn_mfma_f32_32x32x16_bf16(pa.s, v0, oaccL, 0, 0, 0);
      oaccH = __builtin_amdgcn_mfma_f32_32x32x16_bf16(pa.s, v1, oaccH, 0, 0, 0);
      __builtin_amdgcn_s_setprio(0);
    }
  }

  // ---- epilogue ----
  rsum += __shfl_xor(rsum, 32);
  wsHi += __shfl_xor(wsHi, 32);
  if (h == 0) { LROWw[w][l31] = rsum; WHIw[w][l31] = wsHi; }

  if (h == 0) {
    float ms = 0.f;
    #pragma unroll
    for (int cch = 0; cch < 4; ++cch) {
      const short8 v = *(const short8*)&wsAll[w][l31][cch * 8];
      #pragma unroll
      for (int j = 0; j < 8; ++j) ms += bf2f((ushortT)v[j]);
    }
    wsAll[w][l31][0]  = f2bf(rsum - wsHi - ms);
    wsAll[w][l31][32] = f2bf(wsHi);
  }

  // bucket matvec: oacc[q][d] += sum_r wsAll[q][r] * EV[r][d]  (6 MFMAs)
  #pragma unroll
  for (int kk = 0; kk < 3; ++kk) {
    const short8 aw = *(const short8*)&wsAll[w][l31][kk * 16 + h * 8];
    const short8 bL = *(const short8*)&EVT[l31][kk * 16 + h * 8];
    const short8 bH = *(const short8*)&EVT[l31 + 32][kk * 16 + h * 8];
    oaccL = __builtin_amdgcn_mfma_f32_32x32x16_bf16(aw, bL, oaccL, 0, 0, 0);
    oaccH = __builtin_amdgcn_mfma_f32_32x32x16_bf16(aw, bH, oaccH, 0, 0, 0);
  }

  const int dl = l31;
  #pragma unroll
  for (int r = 0; r < 16; ++r) {
    const int qr = (r & 3) + 8 * (r >> 2) + 4 * h;
    const float rinv = 1.f / LROWw[w][qr];
    const long orow = qkb + (long)(q0w + qr) * HD;
    Og[orow + dl] = f2bf(oaccL[r] * rinv);
    Og[orow + dl + 32] = f2bf(oaccH[r] * rinv);
  }
}

extern "C" void kernel_launch(void* const* d_in, const int* in_sizes, int n_in,
                              void* d_out, int out_size, void* d_ws, size_t ws_size,
                              hipStream_t stream) {
  const float* x    = (const float*)d_in[0];
  const int*   mask = (const int*)d_in[1];
  const float* dw_w = (const float*)d_in[2];
  const float* dw_b = (const float*)d_in[3];
  const float* pw_w = (const float*)d_in[4];
  const float* pw_b = (const float*)d_in[5];
  const float* lncg = (const float*)d_in[6];
  const float* lncb = (const float*)d_in[7];
  const float* wq   = (const float*)d_in[8];
  const float* bq   = (const float*)d_in[9];
  const float* wk   = (const float*)d_in[10];
  const float* bk   = (const float*)d_in[11];
  const float* wv   = (const float*)d_in[12];
  const float* bv   = (const float*)d_in[13];
  const float* wo   = (const float*)d_in[14];
  const float* bo   = (const float*)d_in[15];
  const float* ek   = (const float*)d_in[16];
  const float* ev   = (const float*)d_in[17];
  const float* lnag = (const float*)d_in[18];
  const float* lnab = (const float*)d_in[19];
  const float* wff  = (const float*)d_in[20];
  const float* bff  = (const float*)d_in[21];
  const float* lnfg = (const float*)d_in[22];
  const float* lnfb = (const float*)d_in[23];

  float* out = (float*)d_out;
  float* PE   = (float*)d_ws;                      // SEQ*HD f32
  float* NB32 = PE + SEQ * HD;                     // TOK*HD f32 (spare)
  ushortT* ABF = (ushortT*)(NB32 + (long)TOK * HD);// TOK*HD bf16 (activations)
  ushortT* QBF = ABF + (long)TOK * HD;
  ushortT* KBF = QBF + (long)TOK * HD;
  ushortT* VTB = KBF + (long)TOK * HD;             // V fragment layout
  ushortT* WBF = VTB + (long)TOK * HD;             // 7 * HD*HD bf16 weights
  const long WSZ = (long)HD * HD;

  init_kernel<<<SEQ * HD / 256 + 7 * HD * HD / 4 / 256, 256, 0, stream>>>(
      PE, pw_w, pw_w + WSZ, wq, wk, wv, wo, wff, WBF);

  // conv block 0: addpos fused into lndw (LN input) and mgemm MODE 4 (residual)
  lndw_kernel<true><<<BATCH * SEQ / 16, 256, 0, stream>>>(
      x, PE, mask, lncg, lncb, dw_w, dw_b, ABF);
  mgemm512_kernel<4><<<512, 512, 0, stream>>>(ABF, WBF, pw_b, out, nullptr, x, PE, mask);

  lndw_kernel<false><<<BATCH * SEQ / 16, 256, 0, stream>>>(
      out, PE, mask, lncg + HD, lncb + HD, dw_w + HD * 7, dw_b + HD, ABF);
  mgemm512_kernel<2><<<512, 512, 0, stream>>>(ABF, WBF + WSZ, pw_b + HD, out, nullptr,
                                              nullptr, nullptr, nullptr);

  ln_kernel<true><<<TOK, 256, 0, stream>>>(out, lnag, lnab, ABF);
  qkv_kernel<<<dim3(512, 3), 512, 0, stream>>>(ABF, WBF + 2 * WSZ, bq, bk, bv, QBF, KBF, VTB);
  attn_kernel<<<dim3(NHEAD, SEQ / 128, BATCH), 256, 0, stream>>>(QBF, KBF, VTB, ek, ev, ABF);
  mgemm512_kernel<1><<<512, 512, 0, stream>>>(ABF, WBF + 5 * WSZ, bo, out, nullptr,
                                              nullptr, nullptr, nullptr);

  ln_kernel<true><<<TOK, 256, 0, stream>>>(out, lnfg, lnfb, ABF);
  mgemm512_kernel<2><<<512, 512, 0, stream>>>(ABF, WBF + 6 * WSZ, bff, out, nullptr,
                                              nullptr, nullptr, nullptr);
}

// Round 18
// 226.733 us; speedup vs baseline: 1.0264x; 1.0264x over previous
//
#include <hip/hip_runtime.h>

#define SEQ 512
#define HD 512
#define BATCH 32
#define TOK (BATCH * SEQ)   // 16384
#define NHEAD 8
#define DKDIM 64
#define MREL 16
#define NRELV 33

using short8 = __attribute__((ext_vector_type(8))) short;
using f32x4  = __attribute__((ext_vector_type(4))) float;
using f32x16 = __attribute__((ext_vector_type(16))) float;
typedef unsigned short ushortT;

#define AS1 __attribute__((address_space(1)))
#define AS3 __attribute__((address_space(3)))
#define GLDS16(g, l) __builtin_amdgcn_global_load_lds( \
    (const AS1 unsigned int*)(const void*)(g), \
    (AS3 unsigned int*)(void*)(l), 16, 0, 0)

__device__ __forceinline__ ushortT f2bf(float x) {
  union { float f; unsigned u; } c; c.f = x;
  unsigned r = c.u + 0x7FFF + ((c.u >> 16) & 1);
  return (ushortT)(r >> 16);
}

__device__ __forceinline__ float bf2f(ushortT h) {
  union { unsigned u; float f; } c; c.u = (unsigned)h << 16;
  return c.f;
}

// ------- merged init: positional-encoding table + weights f32->bf16 ----------
__global__ __launch_bounds__(256) void init_kernel(
    float* __restrict__ PE,
    const float* __restrict__ s0, const float* __restrict__ s1,
    const float* __restrict__ s2, const float* __restrict__ s3,
    const float* __restrict__ s4, const float* __restrict__ s5,
    const float* __restrict__ s6, ushortT* __restrict__ dst) {
  const int b = blockIdx.x;
  const int t = threadIdx.x;
  if (b < SEQ * HD / 256) {                       // PE part
    const int i = b * 256 + t;
    const int s = i >> 9, h = i & (HD - 1);
    float v = 0.f;
    if (s > 0) {
      const int i2 = h & ~1;
      const float div = expf((float)i2 * (-9.210340371976184f / (float)HD));
      const float ang = (float)(s - 1) * div;
      v = (h & 1) ? cosf(ang) : sinf(ang);
    }
    PE[i] = v;
  } else {                                        // weight-convert part
    const int i = (b - SEQ * HD / 256) * 256 + t; // < 7 * HD*HD/4
    const int region = i >> 16;
    const int off = i & 65535;
    const float* s = region == 0 ? s0 : region == 1 ? s1 : region == 2 ? s2 :
                     region == 3 ? s3 : region == 4 ? s4 : region == 5 ? s5 : s6;
    const float4 v = ((const float4*)s)[off];
    ushort4 o;
    o.x = f2bf(v.x); o.y = f2bf(v.y); o.z = f2bf(v.z); o.w = f2bf(v.w);
    *(ushort4*)&dst[(long)i * 4] = o;
  }
}

// ---------------- LayerNorm, one block per row; bf16 out ----------------
template <bool BF>
__global__ __launch_bounds__(256) void ln_kernel(
    const float* __restrict__ X, const float* __restrict__ g,
    const float* __restrict__ bta, void* __restrict__ Yv) {
  const int row = blockIdx.x;
  const int t = threadIdx.x;
  const float* xr = X + (long)row * HD;
  const float x0 = xr[t], x1 = xr[t + 256];
  float s = x0 + x1, q = x0 * x0 + x1 * x1;
  #pragma unroll
  for (int off = 32; off > 0; off >>= 1) {
    s += __shfl_down(s, off);
    q += __shfl_down(q, off);
  }
  __shared__ float sh[10];
  const int w = t >> 6;
  if ((t & 63) == 0) { sh[w] = s; sh[4 + w] = q; }
  __syncthreads();
  if (t == 0) {
    const float S_ = sh[0] + sh[1] + sh[2] + sh[3];
    const float Q_ = sh[4] + sh[5] + sh[6] + sh[7];
    const float mu = S_ * (1.f / (float)HD);
    const float var = Q_ * (1.f / (float)HD) - mu * mu;
    sh[8] = mu;
    sh[9] = rsqrtf(var + 1e-5f);
  }
  __syncthreads();
  const float mu = sh[8], rstd = sh[9];
  const float y0 = (x0 - mu) * rstd * g[t] + bta[t];
  const float y1 = (x1 - mu) * rstd * g[t + 256] + bta[t + 256];
  if (BF) {
    ushortT* yr = (ushortT*)Yv + (long)row * HD;
    yr[t] = f2bf(y0);
    yr[t + 256] = f2bf(y1);
  } else {
    float* yr = (float*)Yv + (long)row * HD;
    yr[t] = y0;
    yr[t + 256] = y1;
  }
}

// ---- fused [addpos +] LayerNorm + depthwise conv1d (K=7, pad 3) ----
template <bool ADDPE>
__global__ __launch_bounds__(256) void lndw_kernel(
    const float* __restrict__ X, const float* __restrict__ PE,
    const int* __restrict__ mask, const float* __restrict__ g,
    const float* __restrict__ bta, const float* __restrict__ w,
    const float* __restrict__ bias, ushortT* __restrict__ Hout) {
  __shared__ ushortT nls[22][512];        // 22528 B
  const int t = threadIdx.x;
  const int lane = t & 63, wv = t >> 6;
  const int tile = blockIdx.x;            // b*32 + stile
  const int b = tile >> 5;
  const int s0 = (tile & 31) << 4;
  const long rowb = (long)b * SEQ;

  float gr[8], br[8];
  #pragma unroll
  for (int i = 0; i < 2; ++i) {
    const float4 v = *(const float4*)&g[lane * 8 + i * 4];
    gr[i * 4 + 0] = v.x; gr[i * 4 + 1] = v.y; gr[i * 4 + 2] = v.z; gr[i * 4 + 3] = v.w;
    const float4 u = *(const float4*)&bta[lane * 8 + i * 4];
    br[i * 4 + 0] = u.x; br[i * 4 + 1] = u.y; br[i * 4 + 2] = u.z; br[i * 4 + 3] = u.w;
  }

  const short8 zero8 = {};
  for (int rr = wv; rr < 22; rr += 4) {
    const int ss = s0 - 3 + rr;
    if (ss < 0 || ss >= SEQ) {
      *(short8*)&nls[rr][lane * 8] = zero8;
    } else {
      const float* xr = X + (rowb + ss) * HD + lane * 8;
      const float4 v0 = *(const float4*)xr;
      const float4 v1 = *(const float4*)(xr + 4);
      float xv[8] = {v0.x, v0.y, v0.z, v0.w, v1.x, v1.y, v1.z, v1.w};
      if (ADDPE) {
        const float mk = (float)mask[rowb + ss];
        const float4 p0 = *(const float4*)&PE[(long)ss * HD + lane * 8];
        const float4 p1 = *(const float4*)&PE[(long)ss * HD + lane * 8 + 4];
        xv[0] += p0.x * mk; xv[1] += p0.y * mk; xv[2] += p0.z * mk; xv[3] += p0.w * mk;
        xv[4] += p1.x * mk; xv[5] += p1.y * mk; xv[6] += p1.z * mk; xv[7] += p1.w * mk;
      }
      float s = 0.f, q = 0.f;
      #pragma unroll
      for (int j = 0; j < 8; ++j) { s += xv[j]; q += xv[j] * xv[j]; }
      #pragma unroll
      for (int off = 32; off > 0; off >>= 1) {
        s += __shfl_xor(s, off);
        q += __shfl_xor(q, off);
      }
      const float mu = s * (1.f / (float)HD);
      const float var = q * (1.f / (float)HD) - mu * mu;
      const float rstd = rsqrtf(var + 1e-5f);
      short8 o;
      #pragma unroll
      for (int j = 0; j < 8; ++j)
        o[j] = (short)f2bf((xv[j] - mu) * rstd * gr[j] + br[j]);
      *(short8*)&nls[rr][lane * 8] = o;
    }
  }
  __syncthreads();

  const int cg = t & 63, sb = t >> 6;
  const int c0 = cg * 8;
  const int sbase = sb * 4;
  float wr[56];
  #pragma unroll
  for (int i = 0; i < 14; ++i) {
    const float4 v = *(const float4*)&w[c0 * 7 + i * 4];
    wr[i * 4 + 0] = v.x; wr[i * 4 + 1] = v.y;
    wr[i * 4 + 2] = v.z; wr[i * 4 + 3] = v.w;
  }
  float bz[8];
  #pragma unroll
  for (int i = 0; i < 2; ++i) {
    const float4 v = *(const float4*)&bias[c0 + i * 4];
    bz[i * 4 + 0] = v.x; bz[i * 4 + 1] = v.y;
    bz[i * 4 + 2] = v.z; bz[i * 4 + 3] = v.w;
  }

  short8 win[7];
  #pragma unroll
  for (int k = 0; k < 7; ++k)
    win[k] = *(const short8*)&nls[sbase + k][c0];
  #pragma unroll
  for (int u = 0; u < 4; ++u) {
    float acc[8];
    #pragma unroll
    for (int j = 0; j < 8; ++j) acc[j] = bz[j];
    #pragma unroll
    for (int k = 0; k < 7; ++k)
      #pragma unroll
      for (int j = 0; j < 8; ++j)
        acc[j] += bf2f((ushortT)win[k][j]) * wr[j * 7 + k];
    short8 o;
    #pragma unroll
    for (int j = 0; j < 8; ++j) o[j] = (short)f2bf(acc[j]);
    *(short8*)&Hout[(rowb + s0 + sbase + u) * HD + c0] = o;
    if (u < 3) {
      #pragma unroll
      for (int k = 0; k < 6; ++k) win[k] = win[k + 1];
      win[6] = *(const short8*)&nls[sbase + u + 7][c0];
    }
  }
}

// ---- 512-thread (8-wave) GEMM tile body: 128x128, BK=64, 2x4 wave grid ------
__device__ __forceinline__ void gemm_tile512(
    const ushortT* __restrict__ A, const ushortT* __restrict__ W,
    int row0, int col0, int t, ushortT* Als, ushortT* Bls, f32x4 acc[4][2]) {
  const int lane = t & 63, w = t >> 6;
  const int wr = w >> 2, wc = w & 3;          // 2 x 4 waves; wave tile 64x32
  const int l15 = lane & 15, lhi = lane >> 4;
  for (int kt = 0; kt < 8; ++kt) {
    __syncthreads();
    #pragma unroll
    for (int i = 0; i < 2; ++i) {
      const int tl = i * 512 + t;
      const int r = tl >> 3, sl = tl & 7;
      const int sc = sl ^ (r & 7);
      GLDS16(A + (long)(row0 + r) * HD + kt * 64 + sc * 8,
             Als + (i * 512 + w * 64) * 8);
      GLDS16(W + (long)(col0 + r) * HD + kt * 64 + sc * 8,
             Bls + (i * 512 + w * 64) * 8);
    }
    __syncthreads();
    #pragma unroll
    for (int kk = 0; kk < 2; ++kk) {
      short8 af[4], bf[2];
      #pragma unroll
      for (int i = 0; i < 4; ++i) {
        const int ra = wr * 64 + i * 16 + l15;
        af[i] = *(const short8*)&Als[ra * 64 + (((kk * 4 + lhi) ^ (ra & 7)) << 3)];
      }
      #pragma unroll
      for (int j = 0; j < 2; ++j) {
        const int rb = wc * 32 + j * 16 + l15;
        bf[j] = *(const short8*)&Bls[rb * 64 + (((kk * 4 + lhi) ^ (rb & 7)) << 3)];
      }
      #pragma unroll
      for (int mi = 0; mi < 4; ++mi)
        #pragma unroll
        for (int ni = 0; ni < 2; ++ni)
          acc[mi][ni] = __builtin_amdgcn_mfma_f32_16x16x32_bf16(af[mi], bf[ni], acc[mi][ni], 0, 0, 0);
    }
  }
}

// MODE 0: C=G  1: C+=G  2: C+=relu(G)  3: Cb=bf16(G)
// MODE 4: C = (X + PE*mask) + relu(G)   (fused addpos residual, conv block 0)
template <int MODE>
__global__ __launch_bounds__(512) void mgemm512_kernel(
    const ushortT* __restrict__ A, const ushortT* __restrict__ W,
    const float* __restrict__ bias, float* __restrict__ C,
    ushortT* __restrict__ Cb, const float* __restrict__ Xp,
    const float* __restrict__ PEp, const int* __restrict__ maskp) {
  __shared__ ushortT Als[128 * 64];
  __shared__ ushortT Bls[128 * 64];
  const int t = threadIdx.x;
  const int bid = blockIdx.x;
  const int m_blk = (bid & 7) * 16 + ((bid >> 3) & 15);  // XCD-chunked
  const int n_blk = bid >> 7;
  const int row0 = m_blk * 128, col0 = n_blk * 128;
  const int lane = t & 63, w = t >> 6;
  const int wr = w >> 2, wc = w & 3;
  const int l15 = lane & 15, lhi = lane >> 4;

  f32x4 acc[4][2] = {};
  gemm_tile512(A, W, row0, col0, t, Als, Bls, acc);

  #pragma unroll
  for (int ni = 0; ni < 2; ++ni) {
    const int c = col0 + wc * 32 + ni * 16 + l15;
    const float bz = bias[c];
    #pragma unroll
    for (int mi = 0; mi < 4; ++mi) {
      #pragma unroll
      for (int reg = 0; reg < 4; ++reg) {
        const int rrow = row0 + wr * 64 + mi * 16 + lhi * 4 + reg;
        const float g = acc[mi][ni][reg] + bz;
        const long idx = (long)rrow * HD + c;
        if (MODE == 0)      C[idx] = g;
        else if (MODE == 1) C[idx] += g;
        else if (MODE == 2) C[idx] += fmaxf(g, 0.f);
        else if (MODE == 3) Cb[idx] = f2bf(g);
        else {
          const int srow = rrow & (SEQ - 1);
          const float mk = (float)maskp[rrow];
          C[idx] = Xp[idx] + PEp[(long)srow * HD + c] * mk + fmaxf(g, 0.f);
        }
      }
    }
  }
}

// fused QKV (512 threads, 8 waves) writing MFMA-fragment layouts:
// Q/K: off = (((bh*16 + s/32)*4 + dd/16)*2 + (dd/8)&1)*256 + (s%32)*8 + dd%8
// V:   off = (((bh*16 + s/32)*4 + (s%32)/8)*2 + dd/32)*256 + (dd%32)*8 + s%8
__global__ __launch_bounds__(512) void qkv_kernel(
    const ushortT* __restrict__ A, const ushortT* __restrict__ Wbase,
    const float* __restrict__ bq, const float* __restrict__ bk,
    const float* __restrict__ bv, ushortT* __restrict__ Q,
    ushortT* __restrict__ K, ushortT* __restrict__ Vt) {
  __shared__ ushortT Als[128 * 64];
  __shared__ ushortT Bls[128 * 64];
  const int t = threadIdx.x;
  const int z = blockIdx.y;
  const ushortT* W = Wbase + (long)z * HD * HD;
  const float* bias = z == 0 ? bq : z == 1 ? bk : bv;
  const int bid = blockIdx.x;
  const int m_blk = (bid & 7) * 16 + ((bid >> 3) & 15);
  const int n_blk = bid >> 7;
  const int row0 = m_blk * 128, col0 = n_blk * 128;
  const int lane = t & 63, w = t >> 6;
  const int wr = w >> 2, wc = w & 3;
  const int l15 = lane & 15, lhi = lane >> 4;

  f32x4 acc[4][2] = {};
  gemm_tile512(A, W, row0, col0, t, Als, Bls, acc);

  #pragma unroll
  for (int ni = 0; ni < 2; ++ni) {
    const int c = col0 + wc * 32 + ni * 16 + l15;
    const float bz = bias[c];
    #pragma unroll
    for (int mi = 0; mi < 4; ++mi) {
      if (z == 2) {                    // V fragment write (4 consecutive s)
        const int tok0 = row0 + wr * 64 + mi * 16 + lhi * 4;
        const int b = tok0 >> 9, s0 = tok0 & (SEQ - 1);
        const int hh2 = c >> 6, dd = c & 63;
        ushort4 pk;
        pk.x = f2bf(acc[mi][ni][0] + bz);
        pk.y = f2bf(acc[mi][ni][1] + bz);
        pk.z = f2bf(acc[mi][ni][2] + bz);
        pk.w = f2bf(acc[mi][ni][3] + bz);
        const long off = ((((long)(b * NHEAD + hh2) * 16 + (s0 >> 5)) * 4 +
                           ((s0 & 31) >> 3)) * 2 + (dd >> 5)) * 256 +
                         (dd & 31) * 8 + (s0 & 7);
        *(ushort4*)&Vt[off] = pk;
      } else {                          // Q/K fragment write
        ushortT* Cb = (z == 0) ? Q : K;
        const int hh2 = c >> 6, dd = c & 63;
        #pragma unroll
        for (int reg = 0; reg < 4; ++reg) {
          const int rrow = row0 + wr * 64 + mi * 16 + lhi * 4 + reg;
          const int b = rrow >> 9, s = rrow & (SEQ - 1);
          const long off = ((((long)(b * NHEAD + hh2) * 16 + (s >> 5)) * 4 +
                             (dd >> 4)) * 2 + ((dd >> 3) & 1)) * 256 +
                           (s & 31) * 8 + (dd & 7);
          Cb[off] = f2bf(acc[mi][ni][reg] + bz);
        }
      }
    }
  }
}

// ---------------- swapped-QK 32x32 MFMA attention, fragment-layout loads -----
// All Q/K/V loads are lane-contiguous (base + l31*8): 8 lines/instr vs 64.
__global__ __launch_bounds__(512, 4) void attn_kernel(
    const ushortT* __restrict__ Qf, const ushortT* __restrict__ Kf,
    const ushortT* __restrict__ Vf, const float* __restrict__ ekg,
    const float* __restrict__ evg, ushortT* __restrict__ Og) {
  __shared__ ushortT qekL[8][32][34];     // 17408 B
  __shared__ ushortT wsAll[8][32][56];    // 28672 B
  __shared__ ushortT EVT[64][56];         // 7168 B  (EV^T bf16, zero-padded)
  __shared__ float LROWw[8][32];          // 1024 B
  __shared__ float WHIw[8][32];           // 1024 B

  const int t = threadIdx.x;
  const int lane = t & 63, w = t >> 6;
  const int l31 = lane & 31, h = lane >> 5;
  const int hh = blockIdx.x, qb = blockIdx.y, bb = blockIdx.z;
  const int q0w = qb * 256 + w * 32;
  const long qkb = ((long)bb * SEQ) * HD + hh * DKDIM;        // for Og only
  const long fbase = (long)(bb * NHEAD + hh) * 16;            // fragment tiles

  // EVT build (cooperative) + zero own wsAll slice
  for (int i = t; i < 64 * 56; i += 512) {
    const int d = i / 56, r = i % 56;
    EVT[d][r] = (r < NRELV) ? f2bf(evg[r * 64 + d]) : (ushortT)0;
  }
  {
    unsigned* wz = (unsigned*)&wsAll[w][0][0];   // 32*56*2/4 = 896 u32
    #pragma unroll
    for (int i = 0; i < 14; ++i) wz[lane + i * 64] = 0u;
  }
  __syncthreads();

  short8 qB[4];
  #pragma unroll
  for (int kk = 0; kk < 4; ++kk)
    qB[kk] = *(const short8*)&Qf[(((fbase + qb * 8 + w) * 4 + kk) * 2 + h) * 256 + l31 * 8];

  {
    f32x16 qacc = {};
    #pragma unroll
    for (int kk = 0; kk < 4; ++kk) {
      short8 ef;
      #pragma unroll
      for (int j = 0; j < 8; ++j)
        ef[j] = (short)f2bf(ekg[l31 * 64 + kk * 16 + h * 8 + j]);
      qacc = __builtin_amdgcn_mfma_f32_32x32x16_bf16(ef, qB[kk], qacc, 0, 0, 0);
    }
    #pragma unroll
    for (int r = 0; r < 16; ++r) {
      const int rr = (r & 3) + 8 * (r >> 2) + 4 * h;
      qekL[w][l31][rr] = f2bf(qacc[r]);
    }
  }
  float qekHiR = 0.f, qekLoR = 0.f;
  #pragma unroll
  for (int kk = 0; kk < 4; ++kk)
    #pragma unroll
    for (int j = 0; j < 8; ++j) {
      const float qv = bf2f((ushortT)qB[kk][j]);
      const int d = kk * 16 + h * 8 + j;
      qekHiR += qv * ekg[32 * 64 + d];
      qekLoR += qv * ekg[d];
    }
  qekHiR += __shfl_xor(qekHiR, 32);
  qekLoR += __shfl_xor(qekLoR, 32);
  if (h == 0) qekL[w][l31][32] = f2bf(qekHiR);

  const int qg = q0w + l31;
  f32x16 oaccL = {}, oaccH = {};
  float rsum = 0.f, wsHi = 0.f;

  for (int kt = 0; kt < 16; ++kt) {
    const int k0 = kt * 32;
    f32x16 sacc = {};
    __builtin_amdgcn_s_setprio(1);
    #pragma unroll
    for (int kk = 0; kk < 4; ++kk) {
      const short8 kf = *(const short8*)&Kf[(((fbase + kt) * 4 + kk) * 2 + h) * 256 + l31 * 8];
      sacc = __builtin_amdgcn_mfma_f32_32x32x16_bf16(kf, qB[kk], sacc, 0, 0, 0);
    }
    __builtin_amdgcn_s_setprio(0);
    const int dmin = k0 - q0w - 31, dmax = k0 + 31 - q0w;
    if (dmin >= MREL) {
      #pragma unroll
      for (int r = 0; r < 16; ++r) {
        const float p = __expf(sacc[r] + qekHiR);
        sacc[r] = p; rsum += p; wsHi += p;
      }
    } else if (dmax <= -MREL) {
      #pragma unroll
      for (int r = 0; r < 16; ++r) {
        const float p = __expf(sacc[r] + qekLoR);
        sacc[r] = p; rsum += p;
      }
    } else {
      #pragma unroll
      for (int r = 0; r < 16; ++r) {
        const int key = k0 + (r & 3) + 8 * (r >> 2) + 4 * h;
        const int db = key - qg;
        const int rcl = min(max(db, -MREL), MREL) + MREL;
        const float p = __expf(sacc[r] + bf2f(qekL[w][l31][rcl]));
        sacc[r] = p; rsum += p;
        if (db >= MREL)       wsHi += p;
        else if (db > -MREL)  wsAll[w][l31][db + MREL] = f2bf(p);  // slots 1..31
      }
    }
    #pragma unroll
    for (int c = 0; c < 2; ++c) {
      const int rb = c * 8;
      unsigned a0, a1, b0, b1;
      asm("v_cvt_pk_bf16_f32 %0, %1, %2" : "=v"(a0) : "v"(sacc[rb + 0]), "v"(sacc[rb + 1]));
      asm("v_cvt_pk_bf16_f32 %0, %1, %2" : "=v"(a1) : "v"(sacc[rb + 2]), "v"(sacc[rb + 3]));
      asm("v_cvt_pk_bf16_f32 %0, %1, %2" : "=v"(b0) : "v"(sacc[rb + 4]), "v"(sacc[rb + 5]));
      asm("v_cvt_pk_bf16_f32 %0, %1, %2" : "=v"(b1) : "v"(sacc[rb + 6]), "v"(sacc[rb + 7]));
      asm("v_permlane32_swap_b32 %0, %1" : "+v"(a0), "+v"(b0));
      asm("v_permlane32_swap_b32 %0, %1" : "+v"(a1), "+v"(b1));
      union { unsigned u[4]; short8 s; } pa;
      pa.u[0] = a0; pa.u[1] = a1; pa.u[2] = b0; pa.u[3] = b1;
      const short8 v0 = *(const short8*)&Vf[((((fbase + kt) * 4 + c * 2 + h) * 2 + 0) * 256) + l31 * 8];
      const short8 v1 = *(const short8*)&Vf[((((fbase + kt) * 4 + c * 2 + h) * 2 + 1) * 256) + l31 * 8];
      __builtin_amdgcn_s_setprio(1);
      oaccL = __builtin_amdgcn_mfma_f32_32x32x16_bf16(pa.s, v0, oaccL, 0, 0, 0);
      oaccH = __builtin_amdgcn_mfma_f32_32x32x16_bf16(pa.s, v1, oaccH, 0, 0, 0);
      __builtin_amdgcn_s_setprio(0);
    }
  }

  // ---- epilogue ----
  rsum += __shfl_xor(rsum, 32);
  wsHi += __shfl_xor(wsHi, 32);
  if (h == 0) { LROWw[w][l31] = rsum; WHIw[w][l31] = wsHi; }

  if (h == 0) {
    float ms = 0.f;
    #pragma unroll
    for (int cch = 0; cch < 4; ++cch) {
      const short8 v = *(const short8*)&wsAll[w][l31][cch * 8];
      #pragma unroll
      for (int j = 0; j < 8; ++j) ms += bf2f((ushortT)v[j]);
    }
    wsAll[w][l31][0]  = f2bf(rsum - wsHi - ms);
    wsAll[w][l31][32] = f2bf(wsHi);
  }

  // bucket matvec: oacc[q][d] += sum_r wsAll[q][r] * EV[r][d]  (6 MFMAs)
  #pragma unroll
  for (int kk = 0; kk < 3; ++kk) {
    const short8 aw = *(const short8*)&wsAll[w][l31][kk * 16 + h * 8];
    const short8 bL = *(const short8*)&EVT[l31][kk * 16 + h * 8];
    const short8 bH = *(const short8*)&EVT[l31 + 32][kk * 16 + h * 8];
    oaccL = __builtin_amdgcn_mfma_f32_32x32x16_bf16(aw, bL, oaccL, 0, 0, 0);
    oaccH = __builtin_amdgcn_mfma_f32_32x32x16_bf16(aw, bH, oaccH, 0, 0, 0);
  }

  const int dl = l31;
  #pragma unroll
  for (int r = 0; r < 16; ++r) {
    const int qr = (r & 3) + 8 * (r >> 2) + 4 * h;
    const float rinv = 1.f / LROWw[w][qr];
    const long orow = qkb + (long)(q0w + qr) * HD;
    Og[orow + dl] = f2bf(oaccL[r] * rinv);
    Og[orow + dl + 32] = f2bf(oaccH[r] * rinv);
  }
}

extern "C" void kernel_launch(void* const* d_in, const int* in_sizes, int n_in,
                              void* d_out, int out_size, void* d_ws, size_t ws_size,
                              hipStream_t stream) {
  const float* x    = (const float*)d_in[0];
  const int*   mask = (const int*)d_in[1];
  const float* dw_w = (const float*)d_in[2];
  const float* dw_b = (const float*)d_in[3];
  const float* pw_w = (const float*)d_in[4];
  const float* pw_b = (const float*)d_in[5];
  const float* lncg = (const float*)d_in[6];
  const float* lncb = (const float*)d_in[7];
  const float* wq   = (const float*)d_in[8];
  const float* bq   = (const float*)d_in[9];
  const float* wk   = (const float*)d_in[10];
  const float* bk   = (const float*)d_in[11];
  const float* wv   = (const float*)d_in[12];
  const float* bv   = (const float*)d_in[13];
  const float* wo   = (const float*)d_in[14];
  const float* bo   = (const float*)d_in[15];
  const float* ek   = (const float*)d_in[16];
  const float* ev   = (const float*)d_in[17];
  const float* lnag = (const float*)d_in[18];
  const float* lnab = (const float*)d_in[19];
  const float* wff  = (const float*)d_in[20];
  const float* bff  = (const float*)d_in[21];
  const float* lnfg = (const float*)d_in[22];
  const float* lnfb = (const float*)d_in[23];

  float* out = (float*)d_out;
  float* PE   = (float*)d_ws;                      // SEQ*HD f32
  float* NB32 = PE + SEQ * HD;                     // TOK*HD f32 (spare)
  ushortT* ABF = (ushortT*)(NB32 + (long)TOK * HD);// TOK*HD bf16 (activations)
  ushortT* QBF = ABF + (long)TOK * HD;
  ushortT* KBF = QBF + (long)TOK * HD;
  ushortT* VTB = KBF + (long)TOK * HD;             // V fragment layout
  ushortT* WBF = VTB + (long)TOK * HD;             // 7 * HD*HD bf16 weights
  const long WSZ = (long)HD * HD;

  init_kernel<<<SEQ * HD / 256 + 7 * HD * HD / 4 / 256, 256, 0, stream>>>(
      PE, pw_w, pw_w + WSZ, wq, wk, wv, wo, wff, WBF);

  // conv block 0: addpos fused into lndw (LN input) and mgemm MODE 4 (residual)
  lndw_kernel<true><<<BATCH * SEQ / 16, 256, 0, stream>>>(
      x, PE, mask, lncg, lncb, dw_w, dw_b, ABF);
  mgemm512_kernel<4><<<512, 512, 0, stream>>>(ABF, WBF, pw_b, out, nullptr, x, PE, mask);

  lndw_kernel<false><<<BATCH * SEQ / 16, 256, 0, stream>>>(
      out, PE, mask, lncg + HD, lncb + HD, dw_w + HD * 7, dw_b + HD, ABF);
  mgemm512_kernel<2><<<512, 512, 0, stream>>>(ABF, WBF + WSZ, pw_b + HD, out, nullptr,
                                              nullptr, nullptr, nullptr);

  ln_kernel<true><<<TOK, 256, 0, stream>>>(out, lnag, lnab, ABF);
  qkv_kernel<<<dim3(512, 3), 512, 0, stream>>>(ABF, WBF + 2 * WSZ, bq, bk, bv, QBF, KBF, VTB);
  attn_kernel<<<dim3(NHEAD, SEQ / 256, BATCH), 512, 0, stream>>>(QBF, KBF, VTB, ek, ev, ABF);
  mgemm512_kernel<1><<<512, 512, 0, stream>>>(ABF, WBF + 5 * WSZ, bo, out, nullptr,
                                              nullptr, nullptr, nullptr);

  ln_kernel<true><<<TOK, 256, 0, stream>>>(out, lnfg, lnfb, ABF);
  mgemm512_kernel<2><<<512, 512, 0, stream>>>(ABF, WBF + 6 * WSZ, bff, out, nullptr,
                                              nullptr, nullptr, nullptr);
}